// Round 5
// baseline (1411.399 us; speedup 1.0000x reference)
//
#include <hip/hip_runtime.h>

#define B_   128
#define DIM_ 768
#define NH_  12
#define HD_  64
#define N_   256

using short8 = __attribute__((ext_vector_type(8))) short;
using f32x4  = __attribute__((ext_vector_type(4))) float;
typedef unsigned short u16;
typedef unsigned int   u32;

__device__ __forceinline__ u16 f2bf_hi(float f) {
    union { float f; u32 u; } v; v.f = f;
    u32 r = (v.u + 0x7fffu + ((v.u >> 16) & 1u)) >> 16;   // RNE
    return (u16)r;
}
__device__ __forceinline__ float bf2f(u16 h) {
    union { u32 u; float f; } v; v.u = ((u32)h) << 16;
    return v.f;
}

// ---------------------------------------------------------------------------
// bias = face_prior[h,n,m] + rel_table[relidx(n,m), h]   -> [NH, N, N]
// ---------------------------------------------------------------------------
__global__ __launch_bounds__(256) void bias_kernel(
    const float* __restrict__ face_prior, const float* __restrict__ rel_table,
    float* __restrict__ bias)
{
    int idx = blockIdx.x * 256 + threadIdx.x;
    int m = idx & 255;
    int n = (idx >> 8) & 255;
    int h = idx >> 16;
    int rn = n >> 4, cn = n & 15;
    int rm = m >> 4, cm = m & 15;
    int ridx = (rn - rm + 15) * 31 + (cn - cm + 15);
    bias[idx] = face_prior[idx] + rel_table[ridx * NH_ + h];
}

// ---------------------------------------------------------------------------
// split weights: fp32 [count] -> hi/lo bf16 (same layout). n8 = count/8.
// ---------------------------------------------------------------------------
__global__ __launch_bounds__(256) void split_w_kernel(
    const float* __restrict__ in, u16* __restrict__ hi, u16* __restrict__ lo, int n8)
{
    int i = blockIdx.x * 256 + threadIdx.x;
    if (i >= n8) return;
    float4 a = *(const float4*)(in + (size_t)i * 8);
    float4 b = *(const float4*)(in + (size_t)i * 8 + 4);
    float v[8] = {a.x, a.y, a.z, a.w, b.x, b.y, b.z, b.w};
    union { u16 s[8]; uint4 q; } H, L;
    #pragma unroll
    for (int j = 0; j < 8; ++j) {
        u16 h = f2bf_hi(v[j]);
        H.s[j] = h;
        L.s[j] = f2bf_hi(v[j] - bf2f(h));
    }
    *(uint4*)(hi + (size_t)i * 8) = H.q;
    *(uint4*)(lo + (size_t)i * 8) = L.q;
}

// ---------------------------------------------------------------------------
// split + transpose x: [B, 768(k), 256(n)] fp32 -> hi/lo bf16 [B, 256(n), 768(k)]
// grid (12 kt, 4 nt, B)
// ---------------------------------------------------------------------------
__global__ __launch_bounds__(256) void split_transpose_x(
    const float* __restrict__ x, u16* __restrict__ hi, u16* __restrict__ lo)
{
    __shared__ float T[64][65];
    const int b = blockIdx.z, k0 = blockIdx.x * 64, n0 = blockIdx.y * 64;
    const int t = threadIdx.x;
    const float* xb = x + (size_t)b * DIM_ * N_;
    {
        int nn = t & 63, kg = t >> 6;
        #pragma unroll
        for (int r = 0; r < 16; ++r) {
            int kk = r * 4 + kg;
            T[kk][nn] = xb[(size_t)(k0 + kk) * N_ + n0 + nn];
        }
    }
    __syncthreads();
    {
        int kk2 = (t & 31) * 2, ng = t >> 5;
        #pragma unroll
        for (int r = 0; r < 8; ++r) {
            int nn = r * 8 + ng;
            float v0 = T[kk2][nn], v1 = T[kk2 + 1][nn];
            u16 h0 = f2bf_hi(v0), h1 = f2bf_hi(v1);
            u16 l0 = f2bf_hi(v0 - bf2f(h0)), l1 = f2bf_hi(v1 - bf2f(h1));
            size_t o = ((size_t)b * N_ + n0 + nn) * DIM_ + k0 + kk2;
            *(u32*)(hi + o) = (u32)h0 | ((u32)h1 << 16);
            *(u32*)(lo + o) = (u32)l0 | ((u32)l1 << 16);
        }
    }
}

// ---------------------------------------------------------------------------
// Split-bf16 MFMA GEMM with global_load_lds staging.
// S[4] = {Wh, Wl, Xh, Xl} tiles; wave wv stages stream wv (8 x 1KB direct).
// MODE 0: qkv epilogue -> emits qh/ql, kh/kl (hi/lo bf16) and v (bf16).
// MODE 1: proj epilogue -> fp32 out[b, oc, n].
// ---------------------------------------------------------------------------
template<int MODE>
__global__ __launch_bounds__(256) void gemm_split(
    const u16* __restrict__ wh, const u16* __restrict__ wl,
    const u16* __restrict__ xh, const u16* __restrict__ xl,
    const float* __restrict__ bvec, float* __restrict__ outp,
    u16* __restrict__ qh, u16* __restrict__ ql,
    u16* __restrict__ kh, u16* __restrict__ kl, u16* __restrict__ vv,
    int b0, int cb)
{
    __shared__ u16 S[4][128][32];    // 32 KB

    const int tid  = threadIdx.x;
    const int lane = tid & 63;
    const int wv   = tid >> 6;
    const int wr   = wv >> 1;
    const int wc   = wv & 1;
    const int bx = blockIdx.x, by = blockIdx.y;
    const int bl = bx >> 1, half = bx & 1;
    const int b  = b0 + bl;

    const size_t wrow0 = (size_t)by * 128;
    const size_t xrow0 = (MODE == 0 ? (size_t)b * N_ : (size_t)bl * N_) + half * 128;

    // stream assignment (wave-uniform)
    const u16* gb   = (wv == 0) ? wh : (wv == 1) ? wl : (wv == 2) ? xh : xl;
    const size_t g0 = (wv < 2) ? wrow0 : xrow0;
    u16* dst0 = &S[wv][0][0];

    f32x4 acc[4][4];
    #pragma unroll
    for (int i = 0; i < 4; ++i)
        #pragma unroll
        for (int j = 0; j < 4; ++j)
            acc[i][j] = (f32x4){0.f, 0.f, 0.f, 0.f};

    const int lrow = lane & 15;
    const int lkc  = (lane >> 4) * 8;

    for (int k0 = 0; k0 < DIM_; k0 += 32) {
        #pragma unroll
        for (int i = 0; i < 8; ++i) {
            const u16* src = gb + (g0 + i * 16 + (lane >> 2)) * DIM_ + k0 + (lane & 3) * 8;
            __builtin_amdgcn_global_load_lds(
                (const __attribute__((address_space(1))) void*)src,
                (__attribute__((address_space(3))) void*)(dst0 + i * 16 * 32),
                16, 0, 0);
        }
        __syncthreads();

        short8 ah[4], al[4];
        #pragma unroll
        for (int mt = 0; mt < 4; ++mt) {
            int r = wr * 64 + mt * 16 + lrow;
            ah[mt] = *(const short8*)&S[0][r][lkc];
            al[mt] = *(const short8*)&S[1][r][lkc];
        }
        #pragma unroll
        for (int nt = 0; nt < 4; ++nt) {
            int r = wc * 64 + nt * 16 + lrow;
            short8 bh = *(const short8*)&S[2][r][lkc];
            short8 bo = *(const short8*)&S[3][r][lkc];
            #pragma unroll
            for (int mt = 0; mt < 4; ++mt) {
                acc[mt][nt] = __builtin_amdgcn_mfma_f32_16x16x32_bf16(ah[mt], bh, acc[mt][nt], 0, 0, 0);
                acc[mt][nt] = __builtin_amdgcn_mfma_f32_16x16x32_bf16(ah[mt], bo, acc[mt][nt], 0, 0, 0);
                acc[mt][nt] = __builtin_amdgcn_mfma_f32_16x16x32_bf16(al[mt], bh, acc[mt][nt], 0, 0, 0);
            }
        }
        __syncthreads();
    }

    // C/D layout: col = lane&15 (n), row = (lane>>4)*4 + reg (oc)
    const int ocb = by * 128 + wr * 64 + (lane >> 4) * 4;
    const int nb  = half * 128 + wc * 64 + (lane & 15);

    if (MODE == 0) {
        #pragma unroll
        for (int mt = 0; mt < 4; ++mt) {
            int oc = ocb + mt * 16;
            float4 bv = *(const float4*)(bvec + oc);
            int which = oc / DIM_;
            int r = oc - which * DIM_;
            int hh = r >> 6, d = r & 63;
            size_t rowbase = ((size_t)bl * NH_ + hh) * (N_ * HD_) + d;
            #pragma unroll
            for (int nt = 0; nt < 4; ++nt) {
                int n = nb + nt * 16;
                size_t idx = rowbase + (size_t)n * HD_;
                float v0 = acc[mt][nt][0] + bv.x;
                float v1 = acc[mt][nt][1] + bv.y;
                float v2 = acc[mt][nt][2] + bv.z;
                float v3 = acc[mt][nt][3] + bv.w;
                union { u16 s[4]; uint2 u; } H;
                H.s[0] = f2bf_hi(v0); H.s[1] = f2bf_hi(v1);
                H.s[2] = f2bf_hi(v2); H.s[3] = f2bf_hi(v3);
                if (which == 2) {
                    *(uint2*)(vv + idx) = H.u;
                } else {
                    union { u16 s[4]; uint2 u; } L;
                    L.s[0] = f2bf_hi(v0 - bf2f(H.s[0]));
                    L.s[1] = f2bf_hi(v1 - bf2f(H.s[1]));
                    L.s[2] = f2bf_hi(v2 - bf2f(H.s[2]));
                    L.s[3] = f2bf_hi(v3 - bf2f(H.s[3]));
                    u16* ph = (which == 0) ? qh : kh;
                    u16* pl = (which == 0) ? ql : kl;
                    *(uint2*)(ph + idx) = H.u;
                    *(uint2*)(pl + idx) = L.u;
                }
            }
        }
    } else {
        #pragma unroll
        for (int mt = 0; mt < 4; ++mt) {
            int oc = ocb + mt * 16;
            float4 bv = *(const float4*)(bvec + oc);
            float* obase = outp + (size_t)b * DIM_ * N_ + (size_t)oc * N_;
            #pragma unroll
            for (int nt = 0; nt < 4; ++nt) {
                int n = nb + nt * 16;
                obase[0 * N_ + n] = acc[mt][nt][0] + bv.x;
                obase[1 * N_ + n] = acc[mt][nt][1] + bv.y;
                obase[2 * N_ + n] = acc[mt][nt][2] + bv.z;
                obase[3 * N_ + n] = acc[mt][nt][3] + bv.w;
            }
        }
    }
}

// ---------------------------------------------------------------------------
// MFMA attention, 8 waves (512 thr, 2 waves/SIMD). Each wave: 32 q rows.
// S^T = mfma(K, Q); softmax per-lane over kk + shfl 16/32.
// PV in 32-kk chunks via 1KB/wave PL buffer (swizzled, same-wave DS order).
// LDS: Kh 32K | Kl 32K | Vt 32K | PL 8x1K = 104 KB.
// ---------------------------------------------------------------------------
__global__ __launch_bounds__(512, 2) void attn_mfma(
    const u16* __restrict__ qh, const u16* __restrict__ ql,
    const u16* __restrict__ kh, const u16* __restrict__ kl,
    const u16* __restrict__ vv,
    const float* __restrict__ bias, const float* __restrict__ fpri,
    u16* __restrict__ aoh, u16* __restrict__ aol,
    int b0, int cb)
{
    extern __shared__ u16 lds[];
    u16* KhL = lds;            // [256][64], idx = r*64 + (kc ^ ((r&7)<<3))
    u16* KlL = lds + 16384;
    u16* VtL = lds + 32768;    // [64][256], idx = d*256 + (kk ^ ((d&7)<<3))
    const int tid  = threadIdx.x;
    const int lane = tid & 63;
    const int wv   = tid >> 6;                 // 0..7
    u16* PL = lds + 49152 + wv * 512;          // [16][32] per wave

    const int bh = blockIdx.x;
    const int bl = bh / NH_, h = bh % NH_;
    const int b  = b0 + bl;
    const size_t base = ((size_t)bl * NH_ + h) * (size_t)(N_ * HD_);

    // stage K hi/lo (swizzled)
    #pragma unroll
    for (int s = 0; s < 4; ++s) {
        int chunk = tid + s * 512;            // 0..2047
        int r = chunk >> 3, kc = (chunk & 7) * 8;
        int di = r * 64 + (kc ^ ((r & 7) << 3));
        *(short8*)&KhL[di] = *(const short8*)(kh + base + (size_t)r * 64 + kc);
        *(short8*)&KlL[di] = *(const short8*)(kl + base + (size_t)r * 64 + kc);
    }
    // stage V transposed (d-major gather; coalesced across lanes per j)
    #pragma unroll
    for (int s = 0; s < 4; ++s) {
        int chunk = tid + s * 512;
        int d = chunk & 63, kkc = (chunk >> 6) * 8;
        union { u16 s[8]; short8 v; } t;
        #pragma unroll
        for (int j = 0; j < 8; ++j)
            t.s[j] = vv[base + (size_t)(kkc + j) * 64 + d];
        *(short8*)&VtL[d * 256 + (kkc ^ ((d & 7) << 3))] = t.v;
    }
    __syncthreads();

    const int l15 = lane & 15;
    const int lg  = lane >> 4;
    const int e   = (l15 & 3) << 1;            // PL swizzle (even -> b128-safe)

    for (int qt = 0; qt < 2; ++qt) {
        const int qg = wv * 32 + qt * 16 + l15;
        const size_t qrow = base + (size_t)qg * 64;
        short8 bqh[2], bql[2];
        #pragma unroll
        for (int c = 0; c < 2; ++c) {
            bqh[c] = *(const short8*)(qh + qrow + lg * 8 + c * 32);
            bql[c] = *(const short8*)(ql + qrow + lg * 8 + c * 32);
        }

        f32x4 sacc[16];
        const float* brow = bias + ((size_t)h * N_ + qg) * N_;
        const float* frow = fpri + ((size_t)b * N_ + qg) * N_;
        #pragma unroll
        for (int kt = 0; kt < 16; ++kt) {
            f32x4 sa = (f32x4){0.f, 0.f, 0.f, 0.f};
            int kr = kt * 16 + l15;
            #pragma unroll
            for (int c = 0; c < 2; ++c) {
                int kc = lg * 8 + c * 32;
                int di = kr * 64 + (kc ^ ((kr & 7) << 3));
                short8 ah = *(const short8*)&KhL[di];
                short8 al = *(const short8*)&KlL[di];
                sa = __builtin_amdgcn_mfma_f32_16x16x32_bf16(ah, bqh[c], sa, 0, 0, 0);
                sa = __builtin_amdgcn_mfma_f32_16x16x32_bf16(ah, bql[c], sa, 0, 0, 0);
                sa = __builtin_amdgcn_mfma_f32_16x16x32_bf16(al, bqh[c], sa, 0, 0, 0);
            }
            float4 bs = *(const float4*)(brow + kt * 16 + lg * 4);
            float4 fs = *(const float4*)(frow + kt * 16 + lg * 4);
            sacc[kt][0] = (sa[0] * 0.125f + bs.x) * fs.x;
            sacc[kt][1] = (sa[1] * 0.125f + bs.y) * fs.y;
            sacc[kt][2] = (sa[2] * 0.125f + bs.z) * fs.z;
            sacc[kt][3] = (sa[3] * 0.125f + bs.w) * fs.w;
        }

        // softmax over kk (row = qg): per-lane 64 values + shfl 16/32
        float m = -1e30f;
        #pragma unroll
        for (int kt = 0; kt < 16; ++kt)
            m = fmaxf(m, fmaxf(fmaxf(sacc[kt][0], sacc[kt][1]),
                               fmaxf(sacc[kt][2], sacc[kt][3])));
        m = fmaxf(m, __shfl_xor(m, 16));
        m = fmaxf(m, __shfl_xor(m, 32));
        float lsum = 0.f;
        #pragma unroll
        for (int kt = 0; kt < 16; ++kt) {
            #pragma unroll
            for (int j = 0; j < 4; ++j) {
                float p = __expf(sacc[kt][j] - m);
                sacc[kt][j] = p;
                lsum += p;
            }
        }
        lsum += __shfl_xor(lsum, 16);
        lsum += __shfl_xor(lsum, 32);

        // PV in 32-kk chunks: write P chunk to PL, read B-frag, 4 MFMA
        f32x4 oacc[4];
        #pragma unroll
        for (int dt = 0; dt < 4; ++dt) oacc[dt] = (f32x4){0.f, 0.f, 0.f, 0.f};
        #pragma unroll
        for (int c2 = 0; c2 < 8; ++c2) {
            #pragma unroll
            for (int t = 0; t < 2; ++t) {
                int kt = c2 * 2 + t;
                union { u16 s[4]; uint2 u; } pw;
                pw.s[0] = f2bf_hi(sacc[kt][0]);
                pw.s[1] = f2bf_hi(sacc[kt][1]);
                pw.s[2] = f2bf_hi(sacc[kt][2]);
                pw.s[3] = f2bf_hi(sacc[kt][3]);
                int u = (4 * t + lg) ^ e;
                *(uint2*)&PL[l15 * 32 + u * 4] = pw.u;
            }
            short8 bp = *(const short8*)&PL[l15 * 32 + ((2 * lg) ^ e) * 4];
            int kc2 = lg * 8 + c2 * 32;
            #pragma unroll
            for (int dt = 0; dt < 4; ++dt) {
                int dr = dt * 16 + l15;
                short8 av = *(const short8*)&VtL[dr * 256 + (kc2 ^ ((dr & 7) << 3))];
                oacc[dt] = __builtin_amdgcn_mfma_f32_16x16x32_bf16(av, bp, oacc[dt], 0, 0, 0);
            }
        }

        float inv = 1.f / lsum;
        size_t orow = ((size_t)bl * N_ + qg) * DIM_ + h * HD_;
        #pragma unroll
        for (int dt = 0; dt < 4; ++dt) {
            int d0 = dt * 16 + lg * 4;
            union { u16 s[4]; uint2 u; } H, L;
            #pragma unroll
            for (int j = 0; j < 4; ++j) {
                float vf = oacc[dt][j] * inv;
                u16 hh = f2bf_hi(vf);
                H.s[j] = hh;
                L.s[j] = f2bf_hi(vf - bf2f(hh));
            }
            *(uint2*)(aoh + orow + d0) = H.u;
            *(uint2*)(aol + orow + d0) = L.u;
        }
    }
}

// ---------------------------------------------------------------------------
extern "C" void kernel_launch(void* const* d_in, const int* in_sizes, int n_in,
                              void* d_out, int out_size, void* d_ws, size_t ws_size,
                              hipStream_t stream)
{
    const float* x           = (const float*)d_in[0];
    const float* face_priors = (const float*)d_in[1];
    const float* qkv_w       = (const float*)d_in[2];
    const float* qkv_b       = (const float*)d_in[3];
    const float* rel_table   = (const float*)d_in[4];
    const float* face_prior  = (const float*)d_in[5];
    const float* proj_w      = (const float*)d_in[6];
    const float* proj_b      = (const float*)d_in[7];
    float* out = (float*)d_out;

    float* ws   = (float*)d_ws;
    float* bias = ws;
    u16* xah = (u16*)(bias + 786432);
    u16* xal = xah + (size_t)B_ * N_ * DIM_;
    u16* qwh = xal + (size_t)B_ * N_ * DIM_;
    u16* qwl = qwh + (size_t)3 * DIM_ * DIM_;
    u16* pwh = qwl + (size_t)3 * DIM_ * DIM_;
    u16* pwl = pwh + (size_t)DIM_ * DIM_;
    u16* cbase = pwl + (size_t)DIM_ * DIM_;

    int CB = 1;
    const int cands[] = {128, 64, 32, 16, 8, 4, 2, 1};
    for (int ci = 0; ci < 8; ++ci) {
        if (113246208ull + (size_t)cands[ci] * 2752512ull <= ws_size) { CB = cands[ci]; break; }
    }
    const size_t SL = (size_t)CB * NH_ * N_ * HD_;
    u16* qhb = cbase;
    u16* qlb = qhb + SL;
    u16* khb = qlb + SL;
    u16* klb = khb + SL;
    u16* vvb = klb + SL;
    u16* aoh = vvb + SL;
    u16* aol = aoh + (size_t)CB * N_ * DIM_;

    hipFuncSetAttribute((const void*)attn_mfma,
                        hipFuncAttributeMaxDynamicSharedMemorySize, 106496);

    bias_kernel<<<(NH_ * N_ * N_) / 256, 256, 0, stream>>>(face_prior, rel_table, bias);
    split_w_kernel<<<(3 * DIM_ * DIM_ / 8 + 255) / 256, 256, 0, stream>>>(qkv_w, qwh, qwl, 3 * DIM_ * DIM_ / 8);
    split_w_kernel<<<(DIM_ * DIM_ / 8 + 255) / 256, 256, 0, stream>>>(proj_w, pwh, pwl, DIM_ * DIM_ / 8);
    split_transpose_x<<<dim3(12, 4, B_), 256, 0, stream>>>(x, xah, xal);

    for (int b0 = 0; b0 < B_; b0 += CB) {
        gemm_split<0><<<dim3(CB * 2, 18), 256, 0, stream>>>(
            qwh, qwl, xah, xal, qkv_b, nullptr, qhb, qlb, khb, klb, vvb, b0, CB);

        attn_mfma<<<CB * NH_, 512, 106496, stream>>>(
            qhb, qlb, khb, klb, vvb, bias, face_priors, aoh, aol, b0, CB);

        gemm_split<1><<<dim3(CB * 2, 6), 256, 0, stream>>>(
            pwh, pwl, aoh, aol, proj_b, out,
            nullptr, nullptr, nullptr, nullptr, nullptr, b0, CB);
    }
}

// Round 6
// 912.689 us; speedup vs baseline: 1.5464x; 1.5464x over previous
//
#include <hip/hip_runtime.h>

#define B_   128
#define DIM_ 768
#define NH_  12
#define HD_  64
#define N_   256

using short8 = __attribute__((ext_vector_type(8))) short;
using half8  = __attribute__((ext_vector_type(8))) _Float16;
using f32x4  = __attribute__((ext_vector_type(4))) float;
typedef unsigned short u16;
typedef unsigned int   u32;

__device__ __forceinline__ u16 f2bf_hi(float f) {
    union { float f; u32 u; } v; v.f = f;
    u32 r = (v.u + 0x7fffu + ((v.u >> 16) & 1u)) >> 16;   // RNE
    return (u16)r;
}
__device__ __forceinline__ float bf2f(u16 h) {
    union { u32 u; float f; } v; v.u = ((u32)h) << 16;
    return v.f;
}

// ---------------------------------------------------------------------------
// bias = face_prior[h,n,m] + rel_table[relidx(n,m), h]   -> [NH, N, N]
// ---------------------------------------------------------------------------
__global__ __launch_bounds__(256) void bias_kernel(
    const float* __restrict__ face_prior, const float* __restrict__ rel_table,
    float* __restrict__ bias)
{
    int idx = blockIdx.x * 256 + threadIdx.x;
    int m = idx & 255;
    int n = (idx >> 8) & 255;
    int h = idx >> 16;
    int rn = n >> 4, cn = n & 15;
    int rm = m >> 4, cm = m & 15;
    int ridx = (rn - rm + 15) * 31 + (cn - cm + 15);
    bias[idx] = face_prior[idx] + rel_table[ridx * NH_ + h];
}

// ---------------------------------------------------------------------------
// split weights: fp32 -> hi/lo bf16. n8 = count/8.
// ---------------------------------------------------------------------------
__global__ __launch_bounds__(256) void split_w_kernel(
    const float* __restrict__ in, u16* __restrict__ hi, u16* __restrict__ lo, int n8)
{
    int i = blockIdx.x * 256 + threadIdx.x;
    if (i >= n8) return;
    float4 a = *(const float4*)(in + (size_t)i * 8);
    float4 b = *(const float4*)(in + (size_t)i * 8 + 4);
    float v[8] = {a.x, a.y, a.z, a.w, b.x, b.y, b.z, b.w};
    union { u16 s[8]; uint4 q; } H, L;
    #pragma unroll
    for (int j = 0; j < 8; ++j) {
        u16 h = f2bf_hi(v[j]);
        H.s[j] = h;
        L.s[j] = f2bf_hi(v[j] - bf2f(h));
    }
    *(uint4*)(hi + (size_t)i * 8) = H.q;
    *(uint4*)(lo + (size_t)i * 8) = L.q;
}

// fp32 -> fp16 (single), for proj_w
__global__ __launch_bounds__(256) void conv_w_f16(
    const float* __restrict__ in, _Float16* __restrict__ o16, int n8)
{
    int i = blockIdx.x * 256 + threadIdx.x;
    if (i >= n8) return;
    float4 a = *(const float4*)(in + (size_t)i * 8);
    float4 b = *(const float4*)(in + (size_t)i * 8 + 4);
    float v[8] = {a.x, a.y, a.z, a.w, b.x, b.y, b.z, b.w};
    union { _Float16 s[8]; uint4 q; } H;
    #pragma unroll
    for (int j = 0; j < 8; ++j) H.s[j] = (_Float16)v[j];
    *(uint4*)(o16 + (size_t)i * 8) = H.q;
}

// ---------------------------------------------------------------------------
// split + transpose x: [B, 768(k), 256(n)] fp32 -> hi/lo bf16 [B, 256(n), 768(k)]
// ---------------------------------------------------------------------------
__global__ __launch_bounds__(256) void split_transpose_x(
    const float* __restrict__ x, u16* __restrict__ hi, u16* __restrict__ lo)
{
    __shared__ float T[64][65];
    const int b = blockIdx.z, k0 = blockIdx.x * 64, n0 = blockIdx.y * 64;
    const int t = threadIdx.x;
    const float* xb = x + (size_t)b * DIM_ * N_;
    {
        int nn = t & 63, kg = t >> 6;
        #pragma unroll
        for (int r = 0; r < 16; ++r) {
            int kk = r * 4 + kg;
            T[kk][nn] = xb[(size_t)(k0 + kk) * N_ + n0 + nn];
        }
    }
    __syncthreads();
    {
        int kk2 = (t & 31) * 2, ng = t >> 5;
        #pragma unroll
        for (int r = 0; r < 8; ++r) {
            int nn = r * 8 + ng;
            float v0 = T[kk2][nn], v1 = T[kk2 + 1][nn];
            u16 h0 = f2bf_hi(v0), h1 = f2bf_hi(v1);
            u16 l0 = f2bf_hi(v0 - bf2f(h0)), l1 = f2bf_hi(v1 - bf2f(h1));
            size_t o = ((size_t)b * N_ + n0 + nn) * DIM_ + k0 + kk2;
            *(u32*)(hi + o) = (u32)h0 | ((u32)h1 << 16);
            *(u32*)(lo + o) = (u32)l0 | ((u32)l1 << 16);
        }
    }
}

// ---------------------------------------------------------------------------
// QKV GEMM, split-bf16 MFMA, manual uint4 staging (r3-proven).
// q/k blocks (by<12): 3-term. v blocks (by>=12): 1-term, half staging.
// Emits qh/ql, kh/kl (hi/lo bf16) and v (bf16). grid (cb*2, 18).
// ---------------------------------------------------------------------------
__global__ __launch_bounds__(256) void qkv_gemm(
    const u16* __restrict__ wh, const u16* __restrict__ wl,
    const u16* __restrict__ xh, const u16* __restrict__ xl,
    const float* __restrict__ bvec,
    u16* __restrict__ qh, u16* __restrict__ ql,
    u16* __restrict__ kh, u16* __restrict__ kl, u16* __restrict__ vv,
    int b0, int cb)
{
    __shared__ u16 Wh[128][40], Wl[128][40], Xh[128][40], Xl[128][40];

    const int tid  = threadIdx.x;
    const int lane = tid & 63;
    const int wv   = tid >> 6;
    const int wr   = wv >> 1;
    const int wc   = wv & 1;
    const int bx = blockIdx.x, by = blockIdx.y;
    const int bl = bx >> 1, half = bx & 1;
    const int b  = b0 + bl;
    const bool vblk = (by >= 12);

    const size_t wrow0 = (size_t)by * 128;
    const size_t xrow0 = (size_t)b * N_ + half * 128;

    const int srow = tid >> 2;
    const int skc  = tid & 3;

    f32x4 acc[4][4];
    #pragma unroll
    for (int i = 0; i < 4; ++i)
        #pragma unroll
        for (int j = 0; j < 4; ++j)
            acc[i][j] = (f32x4){0.f, 0.f, 0.f, 0.f};

    const int lrow = lane & 15;
    const int lkc  = (lane >> 4) * 8;

    for (int k0 = 0; k0 < DIM_; k0 += 32) {
        #pragma unroll
        for (int s = 0; s < 2; ++s) {
            int row = srow + s * 64;
            int ko  = k0 + skc * 8;
            size_t wsrc = (wrow0 + row) * DIM_ + ko;
            size_t xsrc = (xrow0 + row) * DIM_ + ko;
            *(uint4*)&Wh[row][skc * 8] = *(const uint4*)(wh + wsrc);
            *(uint4*)&Xh[row][skc * 8] = *(const uint4*)(xh + xsrc);
            if (!vblk) {
                *(uint4*)&Wl[row][skc * 8] = *(const uint4*)(wl + wsrc);
                *(uint4*)&Xl[row][skc * 8] = *(const uint4*)(xl + xsrc);
            }
        }
        __syncthreads();

        short8 ah[4], al[4];
        #pragma unroll
        for (int mt = 0; mt < 4; ++mt) {
            int r = wr * 64 + mt * 16 + lrow;
            ah[mt] = *(const short8*)&Wh[r][lkc];
            if (!vblk) al[mt] = *(const short8*)&Wl[r][lkc];
        }
        #pragma unroll
        for (int nt = 0; nt < 4; ++nt) {
            int r = wc * 64 + nt * 16 + lrow;
            short8 bh = *(const short8*)&Xh[r][lkc];
            if (!vblk) {
                short8 bo = *(const short8*)&Xl[r][lkc];
                #pragma unroll
                for (int mt = 0; mt < 4; ++mt) {
                    acc[mt][nt] = __builtin_amdgcn_mfma_f32_16x16x32_bf16(ah[mt], bh, acc[mt][nt], 0, 0, 0);
                    acc[mt][nt] = __builtin_amdgcn_mfma_f32_16x16x32_bf16(ah[mt], bo, acc[mt][nt], 0, 0, 0);
                    acc[mt][nt] = __builtin_amdgcn_mfma_f32_16x16x32_bf16(al[mt], bh, acc[mt][nt], 0, 0, 0);
                }
            } else {
                #pragma unroll
                for (int mt = 0; mt < 4; ++mt)
                    acc[mt][nt] = __builtin_amdgcn_mfma_f32_16x16x32_bf16(ah[mt], bh, acc[mt][nt], 0, 0, 0);
            }
        }
        __syncthreads();
    }

    // C/D layout: col = lane&15 (n), row = (lane>>4)*4 + reg (oc)
    const int ocb = by * 128 + wr * 64 + (lane >> 4) * 4;
    const int nb  = half * 128 + wc * 64 + (lane & 15);

    #pragma unroll
    for (int mt = 0; mt < 4; ++mt) {
        int oc = ocb + mt * 16;
        float4 bv = *(const float4*)(bvec + oc);
        int which = oc / DIM_;
        int r = oc - which * DIM_;
        int hh = r >> 6, d = r & 63;
        size_t rowbase = ((size_t)bl * NH_ + hh) * (N_ * HD_) + d;
        #pragma unroll
        for (int nt = 0; nt < 4; ++nt) {
            int n = nb + nt * 16;
            size_t idx = rowbase + (size_t)n * HD_;
            float v0 = acc[mt][nt][0] + bv.x;
            float v1 = acc[mt][nt][1] + bv.y;
            float v2 = acc[mt][nt][2] + bv.z;
            float v3 = acc[mt][nt][3] + bv.w;
            union { u16 s[4]; uint2 u; } H;
            H.s[0] = f2bf_hi(v0); H.s[1] = f2bf_hi(v1);
            H.s[2] = f2bf_hi(v2); H.s[3] = f2bf_hi(v3);
            if (which == 2) {
                *(uint2*)(vv + idx) = H.u;
            } else {
                union { u16 s[4]; uint2 u; } L;
                L.s[0] = f2bf_hi(v0 - bf2f(H.s[0]));
                L.s[1] = f2bf_hi(v1 - bf2f(H.s[1]));
                L.s[2] = f2bf_hi(v2 - bf2f(H.s[2]));
                L.s[3] = f2bf_hi(v3 - bf2f(H.s[3]));
                u16* ph = (which == 0) ? qh : kh;
                u16* pl = (which == 0) ? ql : kl;
                *(uint2*)(ph + idx) = H.u;
                *(uint2*)(pl + idx) = L.u;
            }
        }
    }
}

// ---------------------------------------------------------------------------
// MFMA attention, flash-chunked: 2 chunks of 128 kk, online softmax.
// 4 waves x 64 q-rows. LDS 52KB -> 3 blocks/CU (3 waves/SIMD).
// S^T = mfma(K, Q), 3-term QK; P,V bf16; emits ao fp16.
// LDS: Kh[128][64] 16K | Kl 16K | Vt[64][128] 16K | PL 4x1K = 52KB.
// ---------------------------------------------------------------------------
__global__ __launch_bounds__(256, 3) void attn_mfma(
    const u16* __restrict__ qh, const u16* __restrict__ ql,
    const u16* __restrict__ kh, const u16* __restrict__ kl,
    const u16* __restrict__ vv,
    const float* __restrict__ bias, const float* __restrict__ fpri,
    _Float16* __restrict__ ao,
    int b0, int cb)
{
    extern __shared__ u16 lds[];
    u16* KhL = lds;            // [128][64], idx = r*64 + (kc ^ ((r&7)<<3))
    u16* KlL = lds + 8192;
    u16* VtL = lds + 16384;    // [64][128], idx = d*128 + (kk ^ ((d&7)<<3))
    const int tid  = threadIdx.x;
    const int lane = tid & 63;
    const int wv   = tid >> 6;                 // 0..3
    u16* PL = lds + 24576 + wv * 512;          // [16][32] per wave

    const int bh = blockIdx.x;
    const int bl = bh / NH_, h = bh % NH_;
    const int b  = b0 + bl;
    const size_t base = ((size_t)bl * NH_ + h) * (size_t)(N_ * HD_);

    const int l15 = lane & 15;
    const int lg  = lane >> 4;
    const int e   = (l15 & 3) << 1;            // PL swizzle

    float mrun[4], lrun[4];
    f32x4 oacc[4][4];
    #pragma unroll
    for (int qt = 0; qt < 4; ++qt) {
        mrun[qt] = -1e30f; lrun[qt] = 0.f;
        #pragma unroll
        for (int dt = 0; dt < 4; ++dt) oacc[qt][dt] = (f32x4){0.f, 0.f, 0.f, 0.f};
    }

    for (int ch = 0; ch < 2; ++ch) {
        __syncthreads();
        // stage K hi/lo chunk (swizzled)
        #pragma unroll
        for (int s = 0; s < 4; ++s) {
            int idx = tid + s * 256;             // 0..1023
            int r = idx >> 3, kc = (idx & 7) * 8;
            int di = r * 64 + (kc ^ ((r & 7) << 3));
            size_t src = base + (size_t)(ch * 128 + r) * 64 + kc;
            *(short8*)&KhL[di] = *(const short8*)(kh + src);
            *(short8*)&KlL[di] = *(const short8*)(kl + src);
        }
        // stage V^T chunk
        #pragma unroll
        for (int s = 0; s < 4; ++s) {
            int idx = tid + s * 256;
            int d = idx & 63, kkc = (idx >> 6) * 8;   // kkc 0..120
            union { u16 s[8]; short8 v; } t;
            #pragma unroll
            for (int j = 0; j < 8; ++j)
                t.s[j] = vv[base + (size_t)(ch * 128 + kkc + j) * 64 + d];
            *(short8*)&VtL[d * 128 + (kkc ^ ((d & 7) << 3))] = t.v;
        }
        __syncthreads();

        for (int qt = 0; qt < 4; ++qt) {
            const int qg = wv * 64 + qt * 16 + l15;
            const size_t qrow = base + (size_t)qg * 64;
            short8 bqh[2], bql[2];
            #pragma unroll
            for (int c = 0; c < 2; ++c) {
                bqh[c] = *(const short8*)(qh + qrow + lg * 8 + c * 32);
                bql[c] = *(const short8*)(ql + qrow + lg * 8 + c * 32);
            }

            f32x4 sacc[8];
            const float* brow = bias + ((size_t)h * N_ + qg) * N_ + ch * 128;
            const float* frow = fpri + ((size_t)b * N_ + qg) * N_ + ch * 128;
            #pragma unroll
            for (int kt = 0; kt < 8; ++kt) {
                f32x4 sa = (f32x4){0.f, 0.f, 0.f, 0.f};
                int kr = kt * 16 + l15;
                #pragma unroll
                for (int c = 0; c < 2; ++c) {
                    int kc = lg * 8 + c * 32;
                    int di = kr * 64 + (kc ^ ((kr & 7) << 3));
                    short8 ah = *(const short8*)&KhL[di];
                    short8 al = *(const short8*)&KlL[di];
                    sa = __builtin_amdgcn_mfma_f32_16x16x32_bf16(ah, bqh[c], sa, 0, 0, 0);
                    sa = __builtin_amdgcn_mfma_f32_16x16x32_bf16(ah, bql[c], sa, 0, 0, 0);
                    sa = __builtin_amdgcn_mfma_f32_16x16x32_bf16(al, bqh[c], sa, 0, 0, 0);
                }
                float4 bs = *(const float4*)(brow + kt * 16 + lg * 4);
                float4 fs = *(const float4*)(frow + kt * 16 + lg * 4);
                sacc[kt][0] = (sa[0] * 0.125f + bs.x) * fs.x;
                sacc[kt][1] = (sa[1] * 0.125f + bs.y) * fs.y;
                sacc[kt][2] = (sa[2] * 0.125f + bs.z) * fs.z;
                sacc[kt][3] = (sa[3] * 0.125f + bs.w) * fs.w;
            }

            // online softmax update for this chunk
            float cmax = -1e30f;
            #pragma unroll
            for (int kt = 0; kt < 8; ++kt)
                cmax = fmaxf(cmax, fmaxf(fmaxf(sacc[kt][0], sacc[kt][1]),
                                         fmaxf(sacc[kt][2], sacc[kt][3])));
            cmax = fmaxf(cmax, __shfl_xor(cmax, 16));
            cmax = fmaxf(cmax, __shfl_xor(cmax, 32));
            float mnew = fmaxf(mrun[qt], cmax);
            float corr = __expf(mrun[qt] - mnew);
            mrun[qt] = mnew;
            float csum = 0.f;
            #pragma unroll
            for (int kt = 0; kt < 8; ++kt) {
                #pragma unroll
                for (int j = 0; j < 4; ++j) {
                    float p = __expf(sacc[kt][j] - mnew);
                    sacc[kt][j] = p;
                    csum += p;
                }
            }
            csum += __shfl_xor(csum, 16);
            csum += __shfl_xor(csum, 32);
            lrun[qt] = lrun[qt] * corr + csum;
            #pragma unroll
            for (int dt = 0; dt < 4; ++dt) {
                oacc[qt][dt][0] *= corr; oacc[qt][dt][1] *= corr;
                oacc[qt][dt][2] *= corr; oacc[qt][dt][3] *= corr;
            }

            // PV in 32-kk sub-chunks via per-wave PL buffer
            #pragma unroll
            for (int c2 = 0; c2 < 4; ++c2) {
                #pragma unroll
                for (int t = 0; t < 2; ++t) {
                    int kt = c2 * 2 + t;
                    union { u16 s[4]; uint2 u; } pw;
                    pw.s[0] = f2bf_hi(sacc[kt][0]);
                    pw.s[1] = f2bf_hi(sacc[kt][1]);
                    pw.s[2] = f2bf_hi(sacc[kt][2]);
                    pw.s[3] = f2bf_hi(sacc[kt][3]);
                    int u = (4 * t + lg) ^ e;
                    *(uint2*)&PL[l15 * 32 + u * 4] = pw.u;
                }
                short8 bp = *(const short8*)&PL[l15 * 32 + ((2 * lg) ^ e) * 4];
                int kc2 = lg * 8 + c2 * 32;
                #pragma unroll
                for (int dt = 0; dt < 4; ++dt) {
                    int dr = dt * 16 + l15;
                    short8 av = *(const short8*)&VtL[dr * 128 + (kc2 ^ ((dr & 7) << 3))];
                    oacc[qt][dt] = __builtin_amdgcn_mfma_f32_16x16x32_bf16(av, bp, oacc[qt][dt], 0, 0, 0);
                }
            }
        }
    }

    // epilogue: scale by 1/l, emit fp16
    #pragma unroll
    for (int qt = 0; qt < 4; ++qt) {
        const int qg = wv * 64 + qt * 16 + l15;
        float inv = 1.f / lrun[qt];
        size_t orow = ((size_t)bl * N_ + qg) * DIM_ + h * HD_;
        #pragma unroll
        for (int dt = 0; dt < 4; ++dt) {
            int d0 = dt * 16 + lg * 4;
            union { _Float16 s[4]; uint2 u; } H;
            #pragma unroll
            for (int j = 0; j < 4; ++j)
                H.s[j] = (_Float16)(oacc[qt][dt][j] * inv);
            *(uint2*)(ao + orow + d0) = H.u;
        }
    }
}

// ---------------------------------------------------------------------------
// Proj GEMM, fp16 1-term. A = proj_w fp16, X = ao fp16. out fp32 [b, oc, n].
// grid (cb*2, 6)
// ---------------------------------------------------------------------------
__global__ __launch_bounds__(256) void proj_gemm(
    const _Float16* __restrict__ wh, const _Float16* __restrict__ ao,
    const float* __restrict__ bvec, float* __restrict__ outp,
    int b0)
{
    __shared__ _Float16 W[128][40], X[128][40];

    const int tid  = threadIdx.x;
    const int lane = tid & 63;
    const int wv   = tid >> 6;
    const int wr   = wv >> 1;
    const int wc   = wv & 1;
    const int bx = blockIdx.x, by = blockIdx.y;
    const int bl = bx >> 1, half = bx & 1;
    const int b  = b0 + bl;

    const size_t wrow0 = (size_t)by * 128;
    const size_t xrow0 = (size_t)bl * N_ + half * 128;

    const int srow = tid >> 2;
    const int skc  = tid & 3;

    f32x4 acc[4][4];
    #pragma unroll
    for (int i = 0; i < 4; ++i)
        #pragma unroll
        for (int j = 0; j < 4; ++j)
            acc[i][j] = (f32x4){0.f, 0.f, 0.f, 0.f};

    const int lrow = lane & 15;
    const int lkc  = (lane >> 4) * 8;

    for (int k0 = 0; k0 < DIM_; k0 += 32) {
        #pragma unroll
        for (int s = 0; s < 2; ++s) {
            int row = srow + s * 64;
            int ko  = k0 + skc * 8;
            *(uint4*)&W[row][skc * 8] = *(const uint4*)(wh + (wrow0 + row) * DIM_ + ko);
            *(uint4*)&X[row][skc * 8] = *(const uint4*)(ao + (xrow0 + row) * DIM_ + ko);
        }
        __syncthreads();

        half8 ah[4];
        #pragma unroll
        for (int mt = 0; mt < 4; ++mt) {
            int r = wr * 64 + mt * 16 + lrow;
            ah[mt] = *(const half8*)&W[r][lkc];
        }
        #pragma unroll
        for (int nt = 0; nt < 4; ++nt) {
            int r = wc * 64 + nt * 16 + lrow;
            half8 bh = *(const half8*)&X[r][lkc];
            #pragma unroll
            for (int mt = 0; mt < 4; ++mt)
                acc[mt][nt] = __builtin_amdgcn_mfma_f32_16x16x32_f16(ah[mt], bh, acc[mt][nt], 0, 0, 0);
        }
        __syncthreads();
    }

    const int ocb = by * 128 + wr * 64 + (lane >> 4) * 4;
    const int nb  = half * 128 + wc * 64 + (lane & 15);

    #pragma unroll
    for (int mt = 0; mt < 4; ++mt) {
        int oc = ocb + mt * 16;
        float4 bv = *(const float4*)(bvec + oc);
        float* obase = outp + (size_t)b * DIM_ * N_ + (size_t)oc * N_;
        #pragma unroll
        for (int nt = 0; nt < 4; ++nt) {
            int n = nb + nt * 16;
            obase[0 * N_ + n] = acc[mt][nt][0] + bv.x;
            obase[1 * N_ + n] = acc[mt][nt][1] + bv.y;
            obase[2 * N_ + n] = acc[mt][nt][2] + bv.z;
            obase[3 * N_ + n] = acc[mt][nt][3] + bv.w;
        }
    }
}

// ---------------------------------------------------------------------------
extern "C" void kernel_launch(void* const* d_in, const int* in_sizes, int n_in,
                              void* d_out, int out_size, void* d_ws, size_t ws_size,
                              hipStream_t stream)
{
    const float* x           = (const float*)d_in[0];
    const float* face_priors = (const float*)d_in[1];
    const float* qkv_w       = (const float*)d_in[2];
    const float* qkv_b       = (const float*)d_in[3];
    const float* rel_table   = (const float*)d_in[4];
    const float* face_prior  = (const float*)d_in[5];
    const float* proj_w      = (const float*)d_in[6];
    const float* proj_b      = (const float*)d_in[7];
    float* out = (float*)d_out;

    // persistent: bias 3.15MB | xah/xal 100.7MB | qwh/qwl 7.08MB | pw16 1.18MB
    float* ws   = (float*)d_ws;
    float* bias = ws;
    u16* xah = (u16*)(bias + 786432);
    u16* xal = xah + (size_t)B_ * N_ * DIM_;
    u16* qwh = xal + (size_t)B_ * N_ * DIM_;
    u16* qwl = qwh + (size_t)3 * DIM_ * DIM_;
    _Float16* pw16 = (_Float16*)(qwl + (size_t)3 * DIM_ * DIM_);
    u16* cbase = (u16*)(pw16 + (size_t)DIM_ * DIM_);

    // per-batch chunk: qh/ql/kh/kl/vv (bf16) + ao (fp16) = 6 * 393216 B
    int CB = 1;
    const int cands[] = {128, 64, 32, 16, 8, 4, 2, 1};
    for (int ci = 0; ci < 8; ++ci) {
        if (112066560ull + (size_t)cands[ci] * 2359296ull <= ws_size) { CB = cands[ci]; break; }
    }
    const size_t SL = (size_t)CB * NH_ * N_ * HD_;
    u16* qhb = cbase;
    u16* qlb = qhb + SL;
    u16* khb = qlb + SL;
    u16* klb = khb + SL;
    u16* vvb = klb + SL;
    _Float16* aob = (_Float16*)(vvb + SL);

    hipFuncSetAttribute((const void*)attn_mfma,
                        hipFuncAttributeMaxDynamicSharedMemorySize, 53248);

    bias_kernel<<<(NH_ * N_ * N_) / 256, 256, 0, stream>>>(face_prior, rel_table, bias);
    split_w_kernel<<<(3 * DIM_ * DIM_ / 8 + 255) / 256, 256, 0, stream>>>(qkv_w, qwh, qwl, 3 * DIM_ * DIM_ / 8);
    conv_w_f16<<<(DIM_ * DIM_ / 8 + 255) / 256, 256, 0, stream>>>(proj_w, pw16, DIM_ * DIM_ / 8);
    split_transpose_x<<<dim3(12, 4, B_), 256, 0, stream>>>(x, xah, xal);

    for (int b0 = 0; b0 < B_; b0 += CB) {
        qkv_gemm<<<dim3(CB * 2, 18), 256, 0, stream>>>(
            qwh, qwl, xah, xal, qkv_b, qhb, qlb, khb, klb, vvb, b0, CB);

        attn_mfma<<<CB * NH_, 256, 53248, stream>>>(
            qhb, qlb, khb, klb, vvb, bias, face_priors, aob, b0, CB);

        proj_gemm<<<dim3(CB * 2, 6), 256, 0, stream>>>(
            pw16, aob, proj_b, out, b0);
    }
}